// Round 4
// baseline (159.975 us; speedup 1.0000x reference)
//
#include <hip/hip_runtime.h>

namespace {

constexpr int B = 32, T = 4096, D = 128;
constexpr float NEG_FILL = -1e30f;
constexpr float ALPHA = 0.5f;
constexpr int ROWS = 64;                     // rows of T per block
constexpr int BLOCKS_PER_B = T / ROWS;       // 64
constexpr int GRID = B * BLOCKS_PER_B;       // 2048 -> ~one residency round
constexpr int THREADS = 256;
constexpr int PASSES = ROWS * D / (THREADS * 4);  // 8 (1024 floats = 8 rows/pass)
constexpr int NKEYS = 4 * B * D;             // 16384

// Monotone float<->uint mapping so unsigned atomicMax == float max.
__device__ __forceinline__ unsigned encf(float x) {
  unsigned b = __float_as_uint(x);
  return (b & 0x80000000u) ? ~b : (b | 0x80000000u);
}
__device__ __forceinline__ float decf(unsigned k) {
  unsigned b = (k & 0x80000000u) ? (k ^ 0x80000000u) : ~k;
  return __uint_as_float(b);
}

__global__ void init_kernel(unsigned* __restrict__ keys) {
  int i = blockIdx.x * blockDim.x + threadIdx.x;
  if (i < NKEYS) keys[i] = encf(NEG_FILL);
}

__global__ __launch_bounds__(THREADS) void seg_kernel(
    const float* __restrict__ outp, const float* __restrict__ labp,
    const int* __restrict__ lens, unsigned* __restrict__ keys,
    float* __restrict__ bsum) {
  const int blk = blockIdx.x;
  const int b = blk >> 6;                    // blk / BLOCKS_PER_B
  const int chunk = blk & (BLOCKS_PER_B - 1);
  const int Li = lens[b];
  const int half = Li >> 1;
  const int row0 = chunk * ROWS;
  const int t = threadIdx.x;
  const int col = (t * 4) & (D - 1);
  const int r0 = t >> 5;                     // 0..7 row offset within a pass
  const size_t base = ((size_t)b * T + (size_t)row0) * (size_t)D + (size_t)(t * 4);

  const bool need1 = row0 < half;                                // cat 0,1
  const bool need2 = (row0 < Li) && (row0 + ROWS > half);        // cat 2,3

  float s = 0.0f;
  __shared__ float sh[4][8][D];              // 16 KiB

  if (need1 | need2) {                       // block-uniform: segment-active path
    float4 mO1 = {NEG_FILL, NEG_FILL, NEG_FILL, NEG_FILL};
    float4 mL1 = mO1, mO2 = mO1, mL2 = mO1;
#pragma unroll 4
    for (int i = 0; i < PASSES; ++i) {
      const float4 o = *(const float4*)(outp + base + (size_t)i * (THREADS * 4));
      const float4 l = *(const float4*)(labp + base + (size_t)i * (THREADS * 4));
      float dx;
      dx = o.x - l.x; s = fmaf(dx, dx, s);
      dx = o.y - l.y; s = fmaf(dx, dx, s);
      dx = o.z - l.z; s = fmaf(dx, dx, s);
      dx = o.w - l.w; s = fmaf(dx, dx, s);
      const int pos = row0 + r0 + 8 * i;
      const bool f1 = pos < half;
      const bool f2 = (pos >= half) & (pos < Li);
      mO1.x = fmaxf(mO1.x, f1 ? o.x : NEG_FILL);
      mO1.y = fmaxf(mO1.y, f1 ? o.y : NEG_FILL);
      mO1.z = fmaxf(mO1.z, f1 ? o.z : NEG_FILL);
      mO1.w = fmaxf(mO1.w, f1 ? o.w : NEG_FILL);
      mL1.x = fmaxf(mL1.x, f1 ? l.x : NEG_FILL);
      mL1.y = fmaxf(mL1.y, f1 ? l.y : NEG_FILL);
      mL1.z = fmaxf(mL1.z, f1 ? l.z : NEG_FILL);
      mL1.w = fmaxf(mL1.w, f1 ? l.w : NEG_FILL);
      mO2.x = fmaxf(mO2.x, f2 ? o.x : NEG_FILL);
      mO2.y = fmaxf(mO2.y, f2 ? o.y : NEG_FILL);
      mO2.z = fmaxf(mO2.z, f2 ? o.z : NEG_FILL);
      mO2.w = fmaxf(mO2.w, f2 ? o.w : NEG_FILL);
      mL2.x = fmaxf(mL2.x, f2 ? l.x : NEG_FILL);
      mL2.y = fmaxf(mL2.y, f2 ? l.y : NEG_FILL);
      mL2.z = fmaxf(mL2.z, f2 ? l.z : NEG_FILL);
      mL2.w = fmaxf(mL2.w, f2 ? l.w : NEG_FILL);
    }
    *(float4*)&sh[0][r0][col] = mO1;
    *(float4*)&sh[1][r0][col] = mL1;
    *(float4*)&sh[2][r0][col] = mO2;
    *(float4*)&sh[3][r0][col] = mL2;
    __syncthreads();
    if (t < D) {
      const int c0 = need1 ? 0 : 2;
      const int c1 = need2 ? 4 : 2;
      for (int c = c0; c < c1; ++c) {
        float m = sh[c][0][t];
#pragma unroll
        for (int r2 = 1; r2 < 8; ++r2) m = fmaxf(m, sh[c][r2][t]);
        atomicMax(&keys[c * B * D + b * D + t], encf(m));
      }
    }
  } else {                                   // pure-sumsq path: no LDS, no barrier
#pragma unroll 4
    for (int i = 0; i < PASSES; ++i) {
      const float4 o = *(const float4*)(outp + base + (size_t)i * (THREADS * 4));
      const float4 l = *(const float4*)(labp + base + (size_t)i * (THREADS * 4));
      float dx;
      dx = o.x - l.x; s = fmaf(dx, dx, s);
      dx = o.y - l.y; s = fmaf(dx, dx, s);
      dx = o.z - l.z; s = fmaf(dx, dx, s);
      dx = o.w - l.w; s = fmaf(dx, dx, s);
    }
  }

  // ---- block reduction of sumsq -> per-block slot ----
  for (int off = 32; off > 0; off >>= 1) s += __shfl_down(s, off, 64);
  __shared__ float swave[4];
  if ((t & 63) == 0) swave[t >> 6] = s;
  __syncthreads();
  if (t == 0) bsum[blk] = swave[0] + swave[1] + swave[2] + swave[3];
}

__global__ __launch_bounds__(256) void final_kernel(
    const unsigned* __restrict__ keys, const float* __restrict__ bsum,
    const int* __restrict__ lens, float* __restrict__ res) {
  const int t = threadIdx.x;
  float s = 0.0f;
  for (int j = t; j < GRID; j += 256) s += bsum[j];
  float lf = 0.0f, ls = 0.0f;
  for (int i = t; i < B * D; i += 256) {
    const int b = i >> 7;                    // i / D
    const float valid = (lens[b] >= 2) ? 1.0f : 0.0f;
    const float d1 = decf(keys[0 * B * D + i]) - decf(keys[1 * B * D + i]);
    const float d2 = decf(keys[2 * B * D + i]) - decf(keys[3 * B * D + i]);
    lf += valid * d1 * d1;
    ls += valid * d2 * d2;
  }
  for (int off = 32; off > 0; off >>= 1) {
    s += __shfl_down(s, off, 64);
    lf += __shfl_down(lf, off, 64);
    ls += __shfl_down(ls, off, 64);
  }
  __shared__ float shb[4], shf[4], shs[4];
  if ((t & 63) == 0) { shb[t >> 6] = s; shf[t >> 6] = lf; shs[t >> 6] = ls; }
  __syncthreads();
  if (t == 0) {
    const float S = shb[0] + shb[1] + shb[2] + shb[3];
    const float LF = shf[0] + shf[1] + shf[2] + shf[3];
    const float LS = shs[0] + shs[1] + shs[2] + shs[3];
    const float base = S / ((float)B * (float)T * (float)D);
    res[0] = base + ALPHA * (LF + LS) / ((float)B * (float)D);
  }
}

}  // namespace

extern "C" void kernel_launch(void* const* d_in, const int* in_sizes, int n_in,
                              void* d_out, int out_size, void* d_ws, size_t ws_size,
                              hipStream_t stream) {
  const float* outputs = (const float*)d_in[0];
  const float* labels = (const float*)d_in[1];
  const int* lengths = (const int*)d_in[2];   // harness delivers integers as int32

  unsigned* keys = (unsigned*)d_ws;
  float* bsum = (float*)((char*)d_ws + (size_t)NKEYS * sizeof(unsigned));

  init_kernel<<<(NKEYS + 255) / 256, 256, 0, stream>>>(keys);
  seg_kernel<<<GRID, THREADS, 0, stream>>>(outputs, labels, lengths, keys, bsum);
  final_kernel<<<1, 256, 0, stream>>>(keys, bsum, lengths, (float*)d_out);
}

// Round 6
// 149.220 us; speedup vs baseline: 1.0721x; 1.0721x over previous
//
#include <hip/hip_runtime.h>

namespace {

constexpr int B = 32, T = 4096, D = 128;
constexpr float NEG_FILL = -1e30f;
constexpr float ALPHA = 0.5f;
constexpr int CHUNK_ROWS = 32;               // rows of T per block
constexpr int CHUNKS = T / CHUNK_ROWS;       // 128
constexpr int GRID = B * CHUNKS;             // 4096 blocks
constexpr int THREADS = 256;
constexpr int ITERS = CHUNK_ROWS * D / (THREADS * 4);  // 4
constexpr int NKEYS = 4 * B * D;             // 16384

typedef float vfloat4 __attribute__((ext_vector_type(4)));  // nontemporal-compatible

// Monotone float<->uint mapping so unsigned atomicMax == float max.
__device__ __forceinline__ unsigned encf(float x) {
  unsigned b = __float_as_uint(x);
  return (b & 0x80000000u) ? ~b : (b | 0x80000000u);
}
__device__ __forceinline__ float decf(unsigned k) {
  unsigned b = (k & 0x80000000u) ? (k ^ 0x80000000u) : ~k;
  return __uint_as_float(b);
}

__global__ void init_kernel(unsigned* __restrict__ keys) {
  int i = blockIdx.x * blockDim.x + threadIdx.x;
  if (i < NKEYS) keys[i] = encf(NEG_FILL);
}

__global__ __launch_bounds__(THREADS) void seg_kernel(
    const float* __restrict__ outp, const float* __restrict__ labp,
    const int* __restrict__ lens, unsigned* __restrict__ keys,
    float* __restrict__ bsum) {
  const int blk = blockIdx.x;
  const int b = blk >> 7;                    // blk / CHUNKS
  const int chunk = blk & (CHUNKS - 1);
  const int Li = lens[b];
  const int half = Li >> 1;
  const int row0 = chunk * CHUNK_ROWS;
  const int t = threadIdx.x;
  const int col = (t * 4) & (D - 1);
  const int rbase = row0 + (t >> 5);         // row of this thread at iter 0
  const size_t base = ((size_t)b * T + (size_t)row0) * (size_t)D + (size_t)(t * 4);

  // ---- issue ALL loads first, nontemporal (single-use stream: no-allocate) ----
  vfloat4 o[ITERS], l[ITERS];
#pragma unroll
  for (int i = 0; i < ITERS; ++i) {
    o[i] = __builtin_nontemporal_load((const vfloat4*)(outp + base + (size_t)i * (THREADS * 4)));
    l[i] = __builtin_nontemporal_load((const vfloat4*)(labp + base + (size_t)i * (THREADS * 4)));
  }

  // ---- sumsq ----
  float s = 0.0f;
#pragma unroll
  for (int i = 0; i < ITERS; ++i) {
    float dx;
    dx = o[i].x - l[i].x; s = fmaf(dx, dx, s);
    dx = o[i].y - l[i].y; s = fmaf(dx, dx, s);
    dx = o[i].z - l[i].z; s = fmaf(dx, dx, s);
    dx = o[i].w - l[i].w; s = fmaf(dx, dx, s);
  }

  // ---- segment maxima (skip entirely if chunk outside both segments) ----
  const bool need1 = row0 < half;                                  // cat 0,1
  const bool need2 = (row0 < Li) && (row0 + CHUNK_ROWS > half);    // cat 2,3
  __shared__ float sh[4][8][D];              // 16 KiB

  if (need1 | need2) {                       // block-uniform
    vfloat4 mO1 = {NEG_FILL, NEG_FILL, NEG_FILL, NEG_FILL};
    vfloat4 mL1 = mO1, mO2 = mO1, mL2 = mO1;
#pragma unroll
    for (int i = 0; i < ITERS; ++i) {
      const int pos = rbase + 8 * i;         // stride 1024 floats = 8 rows
      const bool f1 = pos < half;
      const bool f2 = (pos >= half) & (pos < Li);
      mO1.x = fmaxf(mO1.x, f1 ? o[i].x : NEG_FILL);
      mO1.y = fmaxf(mO1.y, f1 ? o[i].y : NEG_FILL);
      mO1.z = fmaxf(mO1.z, f1 ? o[i].z : NEG_FILL);
      mO1.w = fmaxf(mO1.w, f1 ? o[i].w : NEG_FILL);
      mL1.x = fmaxf(mL1.x, f1 ? l[i].x : NEG_FILL);
      mL1.y = fmaxf(mL1.y, f1 ? l[i].y : NEG_FILL);
      mL1.z = fmaxf(mL1.z, f1 ? l[i].z : NEG_FILL);
      mL1.w = fmaxf(mL1.w, f1 ? l[i].w : NEG_FILL);
      mO2.x = fmaxf(mO2.x, f2 ? o[i].x : NEG_FILL);
      mO2.y = fmaxf(mO2.y, f2 ? o[i].y : NEG_FILL);
      mO2.z = fmaxf(mO2.z, f2 ? o[i].z : NEG_FILL);
      mO2.w = fmaxf(mO2.w, f2 ? o[i].w : NEG_FILL);
      mL2.x = fmaxf(mL2.x, f2 ? l[i].x : NEG_FILL);
      mL2.y = fmaxf(mL2.y, f2 ? l[i].y : NEG_FILL);
      mL2.z = fmaxf(mL2.z, f2 ? l[i].z : NEG_FILL);
      mL2.w = fmaxf(mL2.w, f2 ? l[i].w : NEG_FILL);
    }
    const int r = t >> 5;                    // 0..7
    *(vfloat4*)&sh[0][r][col] = mO1;
    *(vfloat4*)&sh[1][r][col] = mL1;
    *(vfloat4*)&sh[2][r][col] = mO2;
    *(vfloat4*)&sh[3][r][col] = mL2;
    __syncthreads();

    if (t < D) {
      const int c0 = need1 ? 0 : 2;
      const int c1 = need2 ? 4 : 2;
#pragma unroll 4
      for (int c = c0; c < c1; ++c) {
        float m = sh[c][0][t];
#pragma unroll
        for (int r2 = 1; r2 < 8; ++r2) m = fmaxf(m, sh[c][r2][t]);
        atomicMax(&keys[c * B * D + b * D + t], encf(m));
      }
    }
  }

  // ---- block reduction of sumsq -> per-block slot (no atomic, no init) ----
  for (int off = 32; off > 0; off >>= 1) s += __shfl_down(s, off, 64);
  __shared__ float swave[4];
  if ((t & 63) == 0) swave[t >> 6] = s;
  __syncthreads();
  if (t == 0) bsum[blk] = swave[0] + swave[1] + swave[2] + swave[3];
}

__global__ __launch_bounds__(256) void final_kernel(
    const unsigned* __restrict__ keys, const float* __restrict__ bsum,
    const int* __restrict__ lens, float* __restrict__ res) {
  const int t = threadIdx.x;
  float s = 0.0f;
  for (int j = t; j < GRID; j += 256) s += bsum[j];
  float lf = 0.0f, ls = 0.0f;
  for (int i = t; i < B * D; i += 256) {
    const int b = i >> 7;                    // i / D
    const float valid = (lens[b] >= 2) ? 1.0f : 0.0f;
    const float d1 = decf(keys[0 * B * D + i]) - decf(keys[1 * B * D + i]);
    const float d2 = decf(keys[2 * B * D + i]) - decf(keys[3 * B * D + i]);
    lf += valid * d1 * d1;
    ls += valid * d2 * d2;
  }
  for (int off = 32; off > 0; off >>= 1) {
    s += __shfl_down(s, off, 64);
    lf += __shfl_down(lf, off, 64);
    ls += __shfl_down(ls, off, 64);
  }
  __shared__ float shb[4], shf[4], shs[4];
  if ((t & 63) == 0) { shb[t >> 6] = s; shf[t >> 6] = lf; shs[t >> 6] = ls; }
  __syncthreads();
  if (t == 0) {
    const float S = shb[0] + shb[1] + shb[2] + shb[3];
    const float LF = shf[0] + shf[1] + shf[2] + shf[3];
    const float LS = shs[0] + shs[1] + shs[2] + shs[3];
    const float base = S / ((float)B * (float)T * (float)D);
    res[0] = base + ALPHA * (LF + LS) / ((float)B * (float)D);
  }
}

}  // namespace

extern "C" void kernel_launch(void* const* d_in, const int* in_sizes, int n_in,
                              void* d_out, int out_size, void* d_ws, size_t ws_size,
                              hipStream_t stream) {
  const float* outputs = (const float*)d_in[0];
  const float* labels = (const float*)d_in[1];
  const int* lengths = (const int*)d_in[2];   // harness delivers integers as int32

  unsigned* keys = (unsigned*)d_ws;
  float* bsum = (float*)((char*)d_ws + (size_t)NKEYS * sizeof(unsigned));

  init_kernel<<<(NKEYS + 255) / 256, 256, 0, stream>>>(keys);
  seg_kernel<<<GRID, THREADS, 0, stream>>>(outputs, labels, lengths, keys, bsum);
  final_kernel<<<1, 256, 0, stream>>>(keys, bsum, lengths, (float*)d_out);
}

// Round 7
// 149.022 us; speedup vs baseline: 1.0735x; 1.0013x over previous
//
#include <hip/hip_runtime.h>

namespace {

constexpr int B = 32, T = 4096, D = 128;
constexpr float NEG_FILL = -1e30f;
constexpr float ALPHA = 0.5f;
constexpr int CHUNK_ROWS = 32;               // rows of T per block
constexpr int CHUNKS = T / CHUNK_ROWS;       // 128
constexpr int GRID = B * CHUNKS;             // 4096 blocks
constexpr int THREADS = 256;
constexpr int ITERS = CHUNK_ROWS * D / (THREADS * 4);  // 4
constexpr int NKEYS = 4 * B * D;             // 16384

typedef float vfloat4 __attribute__((ext_vector_type(4)));  // nontemporal-compatible

// Monotone float<->uint mapping so unsigned atomicMax == float max.
__device__ __forceinline__ unsigned encf(float x) {
  unsigned b = __float_as_uint(x);
  return (b & 0x80000000u) ? ~b : (b | 0x80000000u);
}
__device__ __forceinline__ float decf(unsigned k) {
  unsigned b = (k & 0x80000000u) ? (k ^ 0x80000000u) : ~k;
  return __uint_as_float(b);
}

__global__ void init_kernel(unsigned* __restrict__ keys) {
  int i = blockIdx.x * blockDim.x + threadIdx.x;
  if (i < NKEYS) keys[i] = encf(NEG_FILL);
}

// min 4 waves/EU (16 waves/CU) -> VGPR cap ~128: lets the allocator keep all
// 8 NT loads in flight instead of re-serializing at 32 VGPRs (R6: VGPR_Count=32).
__global__ __launch_bounds__(THREADS, 4) void seg_kernel(
    const float* __restrict__ outp, const float* __restrict__ labp,
    const int* __restrict__ lens, unsigned* __restrict__ keys,
    float* __restrict__ bsum) {
  const int blk = blockIdx.x;
  const int b = blk >> 7;                    // blk / CHUNKS
  const int chunk = blk & (CHUNKS - 1);
  const int Li = lens[b];
  const int half = Li >> 1;
  const int row0 = chunk * CHUNK_ROWS;
  const int t = threadIdx.x;
  const int col = (t * 4) & (D - 1);
  const int rbase = row0 + (t >> 5);         // row of this thread at iter 0
  const size_t base = ((size_t)b * T + (size_t)row0) * (size_t)D + (size_t)(t * 4);

  // ---- issue ALL loads first, nontemporal (single-use stream: no-allocate) ----
  vfloat4 o[ITERS], l[ITERS];
#pragma unroll
  for (int i = 0; i < ITERS; ++i) {
    o[i] = __builtin_nontemporal_load((const vfloat4*)(outp + base + (size_t)i * (THREADS * 4)));
    l[i] = __builtin_nontemporal_load((const vfloat4*)(labp + base + (size_t)i * (THREADS * 4)));
  }

  // ---- sumsq ----
  float s = 0.0f;
#pragma unroll
  for (int i = 0; i < ITERS; ++i) {
    float dx;
    dx = o[i].x - l[i].x; s = fmaf(dx, dx, s);
    dx = o[i].y - l[i].y; s = fmaf(dx, dx, s);
    dx = o[i].z - l[i].z; s = fmaf(dx, dx, s);
    dx = o[i].w - l[i].w; s = fmaf(dx, dx, s);
  }

  // ---- segment maxima (skip entirely if chunk outside both segments) ----
  const bool need1 = row0 < half;                                  // cat 0,1
  const bool need2 = (row0 < Li) && (row0 + CHUNK_ROWS > half);    // cat 2,3
  __shared__ float sh[4][8][D];              // 16 KiB

  if (need1 | need2) {                       // block-uniform
    vfloat4 mO1 = {NEG_FILL, NEG_FILL, NEG_FILL, NEG_FILL};
    vfloat4 mL1 = mO1, mO2 = mO1, mL2 = mO1;
#pragma unroll
    for (int i = 0; i < ITERS; ++i) {
      const int pos = rbase + 8 * i;         // stride 1024 floats = 8 rows
      const bool f1 = pos < half;
      const bool f2 = (pos >= half) & (pos < Li);
      mO1.x = fmaxf(mO1.x, f1 ? o[i].x : NEG_FILL);
      mO1.y = fmaxf(mO1.y, f1 ? o[i].y : NEG_FILL);
      mO1.z = fmaxf(mO1.z, f1 ? o[i].z : NEG_FILL);
      mO1.w = fmaxf(mO1.w, f1 ? o[i].w : NEG_FILL);
      mL1.x = fmaxf(mL1.x, f1 ? l[i].x : NEG_FILL);
      mL1.y = fmaxf(mL1.y, f1 ? l[i].y : NEG_FILL);
      mL1.z = fmaxf(mL1.z, f1 ? l[i].z : NEG_FILL);
      mL1.w = fmaxf(mL1.w, f1 ? l[i].w : NEG_FILL);
      mO2.x = fmaxf(mO2.x, f2 ? o[i].x : NEG_FILL);
      mO2.y = fmaxf(mO2.y, f2 ? o[i].y : NEG_FILL);
      mO2.z = fmaxf(mO2.z, f2 ? o[i].z : NEG_FILL);
      mO2.w = fmaxf(mO2.w, f2 ? o[i].w : NEG_FILL);
      mL2.x = fmaxf(mL2.x, f2 ? l[i].x : NEG_FILL);
      mL2.y = fmaxf(mL2.y, f2 ? l[i].y : NEG_FILL);
      mL2.z = fmaxf(mL2.z, f2 ? l[i].z : NEG_FILL);
      mL2.w = fmaxf(mL2.w, f2 ? l[i].w : NEG_FILL);
    }
    const int r = t >> 5;                    // 0..7
    *(vfloat4*)&sh[0][r][col] = mO1;
    *(vfloat4*)&sh[1][r][col] = mL1;
    *(vfloat4*)&sh[2][r][col] = mO2;
    *(vfloat4*)&sh[3][r][col] = mL2;
    __syncthreads();

    if (t < D) {
      const int c0 = need1 ? 0 : 2;
      const int c1 = need2 ? 4 : 2;
#pragma unroll 4
      for (int c = c0; c < c1; ++c) {
        float m = sh[c][0][t];
#pragma unroll
        for (int r2 = 1; r2 < 8; ++r2) m = fmaxf(m, sh[c][r2][t]);
        atomicMax(&keys[c * B * D + b * D + t], encf(m));
      }
    }
  }

  // ---- block reduction of sumsq -> per-block slot (no atomic, no init) ----
  for (int off = 32; off > 0; off >>= 1) s += __shfl_down(s, off, 64);
  __shared__ float swave[4];
  if ((t & 63) == 0) swave[t >> 6] = s;
  __syncthreads();
  if (t == 0) bsum[blk] = swave[0] + swave[1] + swave[2] + swave[3];
}

__global__ __launch_bounds__(256) void final_kernel(
    const unsigned* __restrict__ keys, const float* __restrict__ bsum,
    const int* __restrict__ lens, float* __restrict__ res) {
  const int t = threadIdx.x;
  float s = 0.0f;
  for (int j = t; j < GRID; j += 256) s += bsum[j];
  float lf = 0.0f, ls = 0.0f;
  for (int i = t; i < B * D; i += 256) {
    const int b = i >> 7;                    // i / D
    const float valid = (lens[b] >= 2) ? 1.0f : 0.0f;
    const float d1 = decf(keys[0 * B * D + i]) - decf(keys[1 * B * D + i]);
    const float d2 = decf(keys[2 * B * D + i]) - decf(keys[3 * B * D + i]);
    lf += valid * d1 * d1;
    ls += valid * d2 * d2;
  }
  for (int off = 32; off > 0; off >>= 1) {
    s += __shfl_down(s, off, 64);
    lf += __shfl_down(lf, off, 64);
    ls += __shfl_down(ls, off, 64);
  }
  __shared__ float shb[4], shf[4], shs[4];
  if ((t & 63) == 0) { shb[t >> 6] = s; shf[t >> 6] = lf; shs[t >> 6] = ls; }
  __syncthreads();
  if (t == 0) {
    const float S = shb[0] + shb[1] + shb[2] + shb[3];
    const float LF = shf[0] + shf[1] + shf[2] + shf[3];
    const float LS = shs[0] + shs[1] + shs[2] + shs[3];
    const float base = S / ((float)B * (float)T * (float)D);
    res[0] = base + ALPHA * (LF + LS) / ((float)B * (float)D);
  }
}

}  // namespace

extern "C" void kernel_launch(void* const* d_in, const int* in_sizes, int n_in,
                              void* d_out, int out_size, void* d_ws, size_t ws_size,
                              hipStream_t stream) {
  const float* outputs = (const float*)d_in[0];
  const float* labels = (const float*)d_in[1];
  const int* lengths = (const int*)d_in[2];   // harness delivers integers as int32

  unsigned* keys = (unsigned*)d_ws;
  float* bsum = (float*)((char*)d_ws + (size_t)NKEYS * sizeof(unsigned));

  init_kernel<<<(NKEYS + 255) / 256, 256, 0, stream>>>(keys);
  seg_kernel<<<GRID, THREADS, 0, stream>>>(outputs, labels, lengths, keys, bsum);
  final_kernel<<<1, 256, 0, stream>>>(keys, bsum, lengths, (float*)d_out);
}

// Round 8
// 143.337 us; speedup vs baseline: 1.1161x; 1.0397x over previous
//
#include <hip/hip_runtime.h>

namespace {

constexpr int B = 32, T = 4096, D = 128;
constexpr float NEG_FILL = -1e30f;
constexpr float ALPHA = 0.5f;
constexpr int CHUNK_ROWS = 32;               // rows of T per block
constexpr int CHUNKS = T / CHUNK_ROWS;       // 128
constexpr int GRID = B * CHUNKS;             // 4096 blocks
constexpr int THREADS = 256;
constexpr int ITERS = CHUNK_ROWS * D / (THREADS * 4);  // 4
constexpr int NKEYS = 4 * B * D;             // 16384

typedef float vfloat4 __attribute__((ext_vector_type(4)));  // nontemporal-compatible

// Monotone float<->uint mapping so unsigned atomicMax == float max.
__device__ __forceinline__ unsigned encf(float x) {
  unsigned b = __float_as_uint(x);
  return (b & 0x80000000u) ? ~b : (b | 0x80000000u);
}
__device__ __forceinline__ float decf(unsigned k) {
  unsigned b = (k & 0x80000000u) ? (k ^ 0x80000000u) : ~k;
  return __uint_as_float(b);
}

__global__ void init_kernel(unsigned* __restrict__ keys) {
  int i = blockIdx.x * blockDim.x + threadIdx.x;
  if (i < NKEYS) keys[i] = encf(NEG_FILL);
}

__global__ __launch_bounds__(THREADS, 4) void seg_kernel(
    const float* __restrict__ outp, const float* __restrict__ labp,
    const int* __restrict__ lens, unsigned* __restrict__ keys,
    float* __restrict__ bsum) {
  const int blk = blockIdx.x;
  const int b = blk >> 7;                    // blk / CHUNKS
  const int chunk = blk & (CHUNKS - 1);
  const int Li = lens[b];
  const int half = Li >> 1;
  const int row0 = chunk * CHUNK_ROWS;
  const int t = threadIdx.x;
  const int col = (t * 4) & (D - 1);
  const int rbase = row0 + (t >> 5);         // row of this thread at iter 0
  const size_t base = ((size_t)b * T + (size_t)row0) * (size_t)D + (size_t)(t * 4);

  // ---- issue ALL loads first, nontemporal; sched_barrier pins the cluster ----
  vfloat4 o[ITERS], l[ITERS];
#pragma unroll
  for (int i = 0; i < ITERS; ++i) {
    o[i] = __builtin_nontemporal_load((const vfloat4*)(outp + base + (size_t)i * (THREADS * 4)));
    l[i] = __builtin_nontemporal_load((const vfloat4*)(labp + base + (size_t)i * (THREADS * 4)));
  }
  // Forbid the scheduler from sinking loads past this point (it re-fused the
  // load/consume loops in R3-R7: VGPR_Count=32 proves ~2 outstanding loads).
  __builtin_amdgcn_sched_barrier(0);

  // ---- sumsq ----
  float s = 0.0f;
#pragma unroll
  for (int i = 0; i < ITERS; ++i) {
    float dx;
    dx = o[i].x - l[i].x; s = fmaf(dx, dx, s);
    dx = o[i].y - l[i].y; s = fmaf(dx, dx, s);
    dx = o[i].z - l[i].z; s = fmaf(dx, dx, s);
    dx = o[i].w - l[i].w; s = fmaf(dx, dx, s);
  }

  // ---- segment maxima (skip entirely if chunk outside both segments) ----
  const bool need1 = row0 < half;                                  // cat 0,1
  const bool need2 = (row0 < Li) && (row0 + CHUNK_ROWS > half);    // cat 2,3
  __shared__ float sh[4][8][D];              // 16 KiB

  if (need1 | need2) {                       // block-uniform
    vfloat4 mO1 = {NEG_FILL, NEG_FILL, NEG_FILL, NEG_FILL};
    vfloat4 mL1 = mO1, mO2 = mO1, mL2 = mO1;
#pragma unroll
    for (int i = 0; i < ITERS; ++i) {
      const int pos = rbase + 8 * i;         // stride 1024 floats = 8 rows
      const bool f1 = pos < half;
      const bool f2 = (pos >= half) & (pos < Li);
      mO1.x = fmaxf(mO1.x, f1 ? o[i].x : NEG_FILL);
      mO1.y = fmaxf(mO1.y, f1 ? o[i].y : NEG_FILL);
      mO1.z = fmaxf(mO1.z, f1 ? o[i].z : NEG_FILL);
      mO1.w = fmaxf(mO1.w, f1 ? o[i].w : NEG_FILL);
      mL1.x = fmaxf(mL1.x, f1 ? l[i].x : NEG_FILL);
      mL1.y = fmaxf(mL1.y, f1 ? l[i].y : NEG_FILL);
      mL1.z = fmaxf(mL1.z, f1 ? l[i].z : NEG_FILL);
      mL1.w = fmaxf(mL1.w, f1 ? l[i].w : NEG_FILL);
      mO2.x = fmaxf(mO2.x, f2 ? o[i].x : NEG_FILL);
      mO2.y = fmaxf(mO2.y, f2 ? o[i].y : NEG_FILL);
      mO2.z = fmaxf(mO2.z, f2 ? o[i].z : NEG_FILL);
      mO2.w = fmaxf(mO2.w, f2 ? o[i].w : NEG_FILL);
      mL2.x = fmaxf(mL2.x, f2 ? l[i].x : NEG_FILL);
      mL2.y = fmaxf(mL2.y, f2 ? l[i].y : NEG_FILL);
      mL2.z = fmaxf(mL2.z, f2 ? l[i].z : NEG_FILL);
      mL2.w = fmaxf(mL2.w, f2 ? l[i].w : NEG_FILL);
    }
    const int r = t >> 5;                    // 0..7
    *(vfloat4*)&sh[0][r][col] = mO1;
    *(vfloat4*)&sh[1][r][col] = mL1;
    *(vfloat4*)&sh[2][r][col] = mO2;
    *(vfloat4*)&sh[3][r][col] = mL2;
    __syncthreads();

    if (t < D) {
      const int c0 = need1 ? 0 : 2;
      const int c1 = need2 ? 4 : 2;
#pragma unroll 4
      for (int c = c0; c < c1; ++c) {
        float m = sh[c][0][t];
#pragma unroll
        for (int r2 = 1; r2 < 8; ++r2) m = fmaxf(m, sh[c][r2][t]);
        atomicMax(&keys[c * B * D + b * D + t], encf(m));
      }
    }
  }

  // ---- block reduction of sumsq -> per-block slot (no atomic, no init) ----
  for (int off = 32; off > 0; off >>= 1) s += __shfl_down(s, off, 64);
  __shared__ float swave[4];
  if ((t & 63) == 0) swave[t >> 6] = s;
  __syncthreads();
  if (t == 0) bsum[blk] = swave[0] + swave[1] + swave[2] + swave[3];
}

// 1024 threads (16 waves on one CU), vectorized reads: the 1-block finale was
// latency-bound at ~8 us with 4 waves and scalar loads.
__global__ __launch_bounds__(1024) void final_kernel(
    const unsigned* __restrict__ keys, const float* __restrict__ bsum,
    const int* __restrict__ lens, float* __restrict__ res) {
  const int t = threadIdx.x;                 // 0..1023

  // bsum: 4096 floats -> one float4 per thread
  const vfloat4 bs = *(const vfloat4*)(bsum + 4 * t);
  float s = bs.x + bs.y + bs.z + bs.w;

  // keys: 4 cats x 4096 -> one uint4 per cat per thread (i = 4t..4t+3, same b)
  const int i0 = 4 * t;
  const int b = i0 >> 7;
  const float valid = (lens[b] >= 2) ? 1.0f : 0.0f;
  const uint4 k0 = *(const uint4*)(keys + 0 * B * D + i0);
  const uint4 k1 = *(const uint4*)(keys + 1 * B * D + i0);
  const uint4 k2 = *(const uint4*)(keys + 2 * B * D + i0);
  const uint4 k3 = *(const uint4*)(keys + 3 * B * D + i0);
  float lf = 0.0f, ls = 0.0f, d;
  d = decf(k0.x) - decf(k1.x); lf = fmaf(d, d, lf);
  d = decf(k0.y) - decf(k1.y); lf = fmaf(d, d, lf);
  d = decf(k0.z) - decf(k1.z); lf = fmaf(d, d, lf);
  d = decf(k0.w) - decf(k1.w); lf = fmaf(d, d, lf);
  d = decf(k2.x) - decf(k3.x); ls = fmaf(d, d, ls);
  d = decf(k2.y) - decf(k3.y); ls = fmaf(d, d, ls);
  d = decf(k2.z) - decf(k3.z); ls = fmaf(d, d, ls);
  d = decf(k2.w) - decf(k3.w); ls = fmaf(d, d, ls);
  lf *= valid; ls *= valid;

  for (int off = 32; off > 0; off >>= 1) {
    s += __shfl_down(s, off, 64);
    lf += __shfl_down(lf, off, 64);
    ls += __shfl_down(ls, off, 64);
  }
  __shared__ float sb[16], sf[16], ss[16];
  if ((t & 63) == 0) { sb[t >> 6] = s; sf[t >> 6] = lf; ss[t >> 6] = ls; }
  __syncthreads();
  if (t == 0) {
    float S = 0, LF = 0, LS = 0;
#pragma unroll
    for (int w = 0; w < 16; ++w) { S += sb[w]; LF += sf[w]; LS += ss[w]; }
    const float base = S / ((float)B * (float)T * (float)D);
    res[0] = base + ALPHA * (LF + LS) / ((float)B * (float)D);
  }
}

}  // namespace

extern "C" void kernel_launch(void* const* d_in, const int* in_sizes, int n_in,
                              void* d_out, int out_size, void* d_ws, size_t ws_size,
                              hipStream_t stream) {
  const float* outputs = (const float*)d_in[0];
  const float* labels = (const float*)d_in[1];
  const int* lengths = (const int*)d_in[2];   // harness delivers integers as int32

  unsigned* keys = (unsigned*)d_ws;
  float* bsum = (float*)((char*)d_ws + (size_t)NKEYS * sizeof(unsigned));

  init_kernel<<<(NKEYS + 255) / 256, 256, 0, stream>>>(keys);
  seg_kernel<<<GRID, THREADS, 0, stream>>>(outputs, labels, lengths, keys, bsum);
  final_kernel<<<1, 1024, 0, stream>>>(keys, bsum, lengths, (float*)d_out);
}

// Round 9
// 142.343 us; speedup vs baseline: 1.1239x; 1.0070x over previous
//
#include <hip/hip_runtime.h>

namespace {

constexpr int B = 32, T = 4096, D = 128;
constexpr float NEG_FILL = -1e30f;
constexpr float ALPHA = 0.5f;
constexpr int CHUNK_ROWS = 64;               // rows of T per block
constexpr int CHUNKS = T / CHUNK_ROWS;       // 64
constexpr int GRID = B * CHUNKS;             // 2048 blocks = 8 blocks/CU
constexpr int THREADS = 256;
constexpr int ITERS = CHUNK_ROWS * D / (THREADS * 4);  // 8 -> 16 NT loads in flight
constexpr int NKEYS = 4 * B * D;             // 16384

typedef float vfloat4 __attribute__((ext_vector_type(4)));  // nontemporal-compatible
typedef float vfloat2 __attribute__((ext_vector_type(2)));

// Monotone float<->uint mapping so unsigned atomicMax == float max.
__device__ __forceinline__ unsigned encf(float x) {
  unsigned b = __float_as_uint(x);
  return (b & 0x80000000u) ? ~b : (b | 0x80000000u);
}
__device__ __forceinline__ float decf(unsigned k) {
  unsigned b = (k & 0x80000000u) ? (k ^ 0x80000000u) : ~k;
  return __uint_as_float(b);
}

__global__ void init_kernel(unsigned* __restrict__ keys) {
  int i = blockIdx.x * blockDim.x + threadIdx.x;
  if (i < NKEYS) keys[i] = encf(NEG_FILL);
}

__global__ __launch_bounds__(THREADS, 4) void seg_kernel(
    const float* __restrict__ outp, const float* __restrict__ labp,
    const int* __restrict__ lens, unsigned* __restrict__ keys,
    float* __restrict__ bsum) {
  const int blk = blockIdx.x;
  const int b = blk >> 6;                    // blk / CHUNKS
  const int chunk = blk & (CHUNKS - 1);
  const int Li = lens[b];
  const int half = Li >> 1;
  const int row0 = chunk * CHUNK_ROWS;
  const int t = threadIdx.x;
  const int col = (t * 4) & (D - 1);
  const int rbase = row0 + (t >> 5);         // row of this thread at iter 0
  const size_t base = ((size_t)b * T + (size_t)row0) * (size_t)D + (size_t)(t * 4);

  // ---- issue ALL 16 loads first, nontemporal; sched_barrier pins the cluster ----
  vfloat4 o[ITERS], l[ITERS];
#pragma unroll
  for (int i = 0; i < ITERS; ++i) {
    o[i] = __builtin_nontemporal_load((const vfloat4*)(outp + base + (size_t)i * (THREADS * 4)));
    l[i] = __builtin_nontemporal_load((const vfloat4*)(labp + base + (size_t)i * (THREADS * 4)));
  }
  // Forbid the scheduler from sinking loads past this point (pre-R8 it re-fused
  // the load/consume loops: VGPR_Count=32 -> ~2 outstanding loads; R8 proved
  // pinning the cluster wins).
  __builtin_amdgcn_sched_barrier(0);

  // ---- sumsq ----
  float s = 0.0f;
#pragma unroll
  for (int i = 0; i < ITERS; ++i) {
    float dx;
    dx = o[i].x - l[i].x; s = fmaf(dx, dx, s);
    dx = o[i].y - l[i].y; s = fmaf(dx, dx, s);
    dx = o[i].z - l[i].z; s = fmaf(dx, dx, s);
    dx = o[i].w - l[i].w; s = fmaf(dx, dx, s);
  }

  // ---- segment maxima (skip entirely if chunk outside both segments) ----
  const bool need1 = row0 < half;                                  // cat 0,1
  const bool need2 = (row0 < Li) && (row0 + CHUNK_ROWS > half);    // cat 2,3
  __shared__ float sh[4][8][D];              // 16 KiB

  if (need1 | need2) {                       // block-uniform
    vfloat4 mO1 = {NEG_FILL, NEG_FILL, NEG_FILL, NEG_FILL};
    vfloat4 mL1 = mO1, mO2 = mO1, mL2 = mO1;
#pragma unroll
    for (int i = 0; i < ITERS; ++i) {
      const int pos = rbase + 8 * i;         // stride 1024 floats = 8 rows
      const bool f1 = pos < half;
      const bool f2 = (pos >= half) & (pos < Li);
      mO1.x = fmaxf(mO1.x, f1 ? o[i].x : NEG_FILL);
      mO1.y = fmaxf(mO1.y, f1 ? o[i].y : NEG_FILL);
      mO1.z = fmaxf(mO1.z, f1 ? o[i].z : NEG_FILL);
      mO1.w = fmaxf(mO1.w, f1 ? o[i].w : NEG_FILL);
      mL1.x = fmaxf(mL1.x, f1 ? l[i].x : NEG_FILL);
      mL1.y = fmaxf(mL1.y, f1 ? l[i].y : NEG_FILL);
      mL1.z = fmaxf(mL1.z, f1 ? l[i].z : NEG_FILL);
      mL1.w = fmaxf(mL1.w, f1 ? l[i].w : NEG_FILL);
      mO2.x = fmaxf(mO2.x, f2 ? o[i].x : NEG_FILL);
      mO2.y = fmaxf(mO2.y, f2 ? o[i].y : NEG_FILL);
      mO2.z = fmaxf(mO2.z, f2 ? o[i].z : NEG_FILL);
      mO2.w = fmaxf(mO2.w, f2 ? o[i].w : NEG_FILL);
      mL2.x = fmaxf(mL2.x, f2 ? l[i].x : NEG_FILL);
      mL2.y = fmaxf(mL2.y, f2 ? l[i].y : NEG_FILL);
      mL2.z = fmaxf(mL2.z, f2 ? l[i].z : NEG_FILL);
      mL2.w = fmaxf(mL2.w, f2 ? l[i].w : NEG_FILL);
    }
    const int r = t >> 5;                    // 0..7
    *(vfloat4*)&sh[0][r][col] = mO1;
    *(vfloat4*)&sh[1][r][col] = mL1;
    *(vfloat4*)&sh[2][r][col] = mO2;
    *(vfloat4*)&sh[3][r][col] = mL2;
    __syncthreads();

    if (t < D) {
      const int c0 = need1 ? 0 : 2;
      const int c1 = need2 ? 4 : 2;
#pragma unroll 4
      for (int c = c0; c < c1; ++c) {
        float m = sh[c][0][t];
#pragma unroll
        for (int r2 = 1; r2 < 8; ++r2) m = fmaxf(m, sh[c][r2][t]);
        atomicMax(&keys[c * B * D + b * D + t], encf(m));
      }
    }
  }

  // ---- block reduction of sumsq -> per-block slot (no atomic, no init) ----
  for (int off = 32; off > 0; off >>= 1) s += __shfl_down(s, off, 64);
  __shared__ float swave[4];
  if ((t & 63) == 0) swave[t >> 6] = s;
  __syncthreads();
  if (t == 0) bsum[blk] = swave[0] + swave[1] + swave[2] + swave[3];
}

// 1024 threads (16 waves on one CU), vectorized reads.
__global__ __launch_bounds__(1024) void final_kernel(
    const unsigned* __restrict__ keys, const float* __restrict__ bsum,
    const int* __restrict__ lens, float* __restrict__ res) {
  const int t = threadIdx.x;                 // 0..1023

  // bsum: 2048 floats -> one float2 per thread
  const vfloat2 bs = *(const vfloat2*)(bsum + 2 * t);
  float s = bs.x + bs.y;

  // keys: 4 cats x 4096 -> one uint4 per cat per thread (i = 4t..4t+3, same b)
  const int i0 = 4 * t;
  const int b = i0 >> 7;
  const float valid = (lens[b] >= 2) ? 1.0f : 0.0f;
  const uint4 k0 = *(const uint4*)(keys + 0 * B * D + i0);
  const uint4 k1 = *(const uint4*)(keys + 1 * B * D + i0);
  const uint4 k2 = *(const uint4*)(keys + 2 * B * D + i0);
  const uint4 k3 = *(const uint4*)(keys + 3 * B * D + i0);
  float lf = 0.0f, ls = 0.0f, d;
  d = decf(k0.x) - decf(k1.x); lf = fmaf(d, d, lf);
  d = decf(k0.y) - decf(k1.y); lf = fmaf(d, d, lf);
  d = decf(k0.z) - decf(k1.z); lf = fmaf(d, d, lf);
  d = decf(k0.w) - decf(k1.w); lf = fmaf(d, d, lf);
  d = decf(k2.x) - decf(k3.x); ls = fmaf(d, d, ls);
  d = decf(k2.y) - decf(k3.y); ls = fmaf(d, d, ls);
  d = decf(k2.z) - decf(k3.z); ls = fmaf(d, d, ls);
  d = decf(k2.w) - decf(k3.w); ls = fmaf(d, d, ls);
  lf *= valid; ls *= valid;

  for (int off = 32; off > 0; off >>= 1) {
    s += __shfl_down(s, off, 64);
    lf += __shfl_down(lf, off, 64);
    ls += __shfl_down(ls, off, 64);
  }
  __shared__ float sb[16], sf[16], ss[16];
  if ((t & 63) == 0) { sb[t >> 6] = s; sf[t >> 6] = lf; ss[t >> 6] = ls; }
  __syncthreads();
  if (t == 0) {
    float S = 0, LF = 0, LS = 0;
#pragma unroll
    for (int w = 0; w < 16; ++w) { S += sb[w]; LF += sf[w]; LS += ss[w]; }
    const float base = S / ((float)B * (float)T * (float)D);
    res[0] = base + ALPHA * (LF + LS) / ((float)B * (float)D);
  }
}

}  // namespace

extern "C" void kernel_launch(void* const* d_in, const int* in_sizes, int n_in,
                              void* d_out, int out_size, void* d_ws, size_t ws_size,
                              hipStream_t stream) {
  const float* outputs = (const float*)d_in[0];
  const float* labels = (const float*)d_in[1];
  const int* lengths = (const int*)d_in[2];   // harness delivers integers as int32

  unsigned* keys = (unsigned*)d_ws;
  float* bsum = (float*)((char*)d_ws + (size_t)NKEYS * sizeof(unsigned));

  init_kernel<<<(NKEYS + 255) / 256, 256, 0, stream>>>(keys);
  seg_kernel<<<GRID, THREADS, 0, stream>>>(outputs, labels, lengths, keys, bsum);
  final_kernel<<<1, 1024, 0, stream>>>(keys, bsum, lengths, (float*)d_out);
}